// Round 6
// baseline (237.517 us; speedup 1.0000x reference)
//
#include <hip/hip_runtime.h>
#include <hip/hip_bf16.h>

// ---------------------------------------------------------------------------
// LengthRegulator (scatter formulation, wide-store tune):
//   x   [B, T, C]  float32
//   dur [B, T]     int32
//   out [B, T_out, C]; out[b,t,:] = x[b, idx, :],
//     idx = upper_bound(cumsum(max(dur,0))[b,:], t) clamped to T-1.
//   T_out recovered from out_size: T_out = out_size / (B*C).
//
// Kernel 1: per-row inclusive cumsum of dur -> cum (B*T ints in d_ws).
// Kernel 2: one 512-thread block per source token (b,j): reads its 2 KB row
//   of x ONCE (nontemporal), writes it into out rows [cum[j-1], cum[j])
//   FOUR rows per iteration (8 KB in flight/block-iter) with nontemporal
//   stores. Clamp tail [cum[T-1], T_out) split across NTAIL blocks per row.
// HBM traffic: read x exactly once (64 MB) + write out once (~184 MB).
// ---------------------------------------------------------------------------

#define LR_T   512  // tokens per row (fixed by setup_inputs)
#define NTAIL  64   // blocks per batch row for the clamp tail

// clang vector type: __builtin_nontemporal_* accepts vectors of float,
// but NOT HIP's struct-based float4.
typedef float vfloat4 __attribute__((ext_vector_type(4)));

__global__ void lr_cumsum_kernel(const int* __restrict__ dur,
                                 int* __restrict__ cum, int T) {
    __shared__ int s[LR_T];
    const int b = blockIdx.x;
    const int tid = threadIdx.x;
    int v = dur[(size_t)b * T + tid];
    v = v > 0 ? v : 0;  // jnp.maximum(dur, 0)
    s[tid] = v;
    __syncthreads();
    for (int off = 1; off < LR_T; off <<= 1) {
        int add = (tid >= off) ? s[tid - off] : 0;
        __syncthreads();
        s[tid] += add;
        __syncthreads();
    }
    cum[(size_t)b * T + tid] = s[tid];
}

__global__ void __launch_bounds__(512)
lr_scatter_kernel(const vfloat4* __restrict__ x4,
                  const int* __restrict__ cum,
                  vfloat4* __restrict__ out4,
                  int T, int T_out) {
    const int jj   = blockIdx.x;     // source token, or T..T+NTAIL-1 for tail
    const int b    = blockIdx.y;     // batch row
    const int tid  = threadIdx.x;    // 0..511
    const int lane = tid & 127;      // float4 lane within a C=512 row
    const int quad = tid >> 7;       // which row of the 4-row group

    const int* crow = cum + (size_t)b * T;
    int j, start, end;
    if (jj < T) {
        j = jj;
        if (jj > 0) {
            // one 8 B load for both boundaries
            const int2 se = *(const int2*)(crow + jj - 1);
            start = se.x;
            end   = se.y;
        } else {
            start = 0;
            end   = crow[0];
        }
    } else {
        // Clamp tail: frames [crow[T-1], T_out) all replicate row T-1.
        j = T - 1;
        const int tstart = crow[T - 1];
        const int tlen   = T_out - tstart;
        if (tlen <= 0) return;
        const int chunk = (tlen + NTAIL - 1) / NTAIL;
        const int k     = jj - T;
        start = tstart + k * chunk;
        end   = start + chunk;
        if (end > T_out) end = T_out;
    }
    if (start >= end) return;  // dur == 0, or empty tail slice

    // Read this token's row once: 128 lanes x 16 B = 2 KB (streamed).
    const vfloat4 val =
        __builtin_nontemporal_load(&x4[((size_t)b * T + j) * 128 + lane]);

    // Four output rows per iteration, nontemporal streaming stores.
    vfloat4* const base = out4 + (size_t)b * T_out * 128 + lane;
    vfloat4* dst = base + ((size_t)start + quad) * 128;
    for (int t = start + quad; t < end; t += 4) {
        __builtin_nontemporal_store(val, dst);
        dst += 512;
    }
}

extern "C" void kernel_launch(void* const* d_in, const int* in_sizes, int n_in,
                              void* d_out, int out_size, void* d_ws, size_t ws_size,
                              hipStream_t stream) {
    const float* x   = (const float*)d_in[0];
    const int*   dur = (const int*)d_in[1];
    float*       out = (float*)d_out;

    const int B  = 32;
    const int BT = in_sizes[1];            // B*T
    const int T  = BT / B;                 // 512
    const int C  = in_sizes[0] / BT;       // 512 (row = 128 float4)
    const int T_out = out_size / (B * C);  // data-dependent, encoded in out_size

    int* cum = (int*)d_ws;                 // B*T ints = 64 KB scratch

    lr_cumsum_kernel<<<B, T, 0, stream>>>(dur, cum, T);

    dim3 grid(T + NTAIL, B);               // source tokens + tail slices
    lr_scatter_kernel<<<grid, 512, 0, stream>>>(
        (const vfloat4*)x, cum, (vfloat4*)out, T, T_out);
}

// Round 7
// 230.458 us; speedup vs baseline: 1.0306x; 1.0306x over previous
//
#include <hip/hip_runtime.h>
#include <hip/hip_bf16.h>

// ---------------------------------------------------------------------------
// LengthRegulator (scatter formulation — measured-best config, R5 revert):
//   x   [B, T, C]  float32
//   dur [B, T]     int32
//   out [B, T_out, C]; out[b,t,:] = x[b, idx, :],
//     idx = upper_bound(cumsum(max(dur,0))[b,:], t) clamped to T-1.
//   T_out recovered from out_size: T_out = out_size / (B*C).
//
// Kernel 1: per-row inclusive cumsum of dur -> cum (B*T ints in d_ws).
// Kernel 2: one 256-thread block per source token (b,j): reads its 2 KB row
//   of x ONCE (nontemporal), writes it into out rows [cum[j-1], cum[j]) two
//   rows per iteration with nontemporal stores. Clamp tail [cum[T-1], T_out)
//   split across NTAIL blocks per batch row.
// HBM traffic: read x exactly once (64 MB) + write out once (~184 MB).
// Tuning history: 128thr 1-row = 246 µs; 256thr 2-row NT = 231.8 µs (best);
// 512thr 4-row NT = 237.5 µs (regression — short spans leave quads idle).
// ---------------------------------------------------------------------------

#define LR_T   512  // tokens per row (fixed by setup_inputs)
#define NTAIL  64   // blocks per batch row for the clamp tail

// clang vector type: __builtin_nontemporal_* accepts vectors of float,
// but NOT HIP's struct-based float4.
typedef float vfloat4 __attribute__((ext_vector_type(4)));

__global__ void lr_cumsum_kernel(const int* __restrict__ dur,
                                 int* __restrict__ cum, int T) {
    __shared__ int s[LR_T];
    const int b = blockIdx.x;
    const int tid = threadIdx.x;
    int v = dur[(size_t)b * T + tid];
    v = v > 0 ? v : 0;  // jnp.maximum(dur, 0)
    s[tid] = v;
    __syncthreads();
    for (int off = 1; off < LR_T; off <<= 1) {
        int add = (tid >= off) ? s[tid - off] : 0;
        __syncthreads();
        s[tid] += add;
        __syncthreads();
    }
    cum[(size_t)b * T + tid] = s[tid];
}

__global__ void __launch_bounds__(256)
lr_scatter_kernel(const vfloat4* __restrict__ x4,
                  const int* __restrict__ cum,
                  vfloat4* __restrict__ out4,
                  int T, int T_out) {
    const int jj   = blockIdx.x;     // source token, or T..T+NTAIL-1 for tail
    const int b    = blockIdx.y;     // batch row
    const int tid  = threadIdx.x;    // 0..255
    const int lane = tid & 127;      // float4 lane within a C=512 row
    const int half = tid >> 7;       // which row of the pair this thread writes

    const int* crow = cum + (size_t)b * T;
    int j, start, end;
    if (jj < T) {
        j = jj;
        if (jj > 0) {
            // one 8 B load for both span boundaries
            const int2 se = *(const int2*)(crow + jj - 1);
            start = se.x;
            end   = se.y;
        } else {
            start = 0;
            end   = crow[0];
        }
    } else {
        // Clamp tail: frames [crow[T-1], T_out) all replicate row T-1.
        j = T - 1;
        const int tstart = crow[T - 1];
        const int tlen   = T_out - tstart;
        if (tlen <= 0) return;
        const int chunk = (tlen + NTAIL - 1) / NTAIL;
        const int k     = jj - T;
        start = tstart + k * chunk;
        end   = start + chunk;
        if (end > T_out) end = T_out;
    }
    if (start >= end) return;  // dur == 0, or empty tail slice

    // Read this token's row once: 128 lanes x 16 B = 2 KB (streamed).
    const vfloat4 val =
        __builtin_nontemporal_load(&x4[((size_t)b * T + j) * 128 + lane]);

    // Two output rows per iteration, nontemporal streaming stores.
    vfloat4* const base = out4 + (size_t)b * T_out * 128 + lane;
    vfloat4* dst = base + ((size_t)start + half) * 128;
    for (int t = start + half; t < end; t += 2) {
        __builtin_nontemporal_store(val, dst);
        dst += 256;
    }
}

extern "C" void kernel_launch(void* const* d_in, const int* in_sizes, int n_in,
                              void* d_out, int out_size, void* d_ws, size_t ws_size,
                              hipStream_t stream) {
    const float* x   = (const float*)d_in[0];
    const int*   dur = (const int*)d_in[1];
    float*       out = (float*)d_out;

    const int B  = 32;
    const int BT = in_sizes[1];            // B*T
    const int T  = BT / B;                 // 512
    const int C  = in_sizes[0] / BT;       // 512 (row = 128 float4)
    const int T_out = out_size / (B * C);  // data-dependent, encoded in out_size

    int* cum = (int*)d_ws;                 // B*T ints = 64 KB scratch

    lr_cumsum_kernel<<<B, T, 0, stream>>>(dur, cum, T);

    dim3 grid(T + NTAIL, B);               // source tokens + tail slices
    lr_scatter_kernel<<<grid, 256, 0, stream>>>(
        (const vfloat4*)x, cum, (vfloat4*)out, T, T_out);
}